// Round 2
// baseline (20.450 us; speedup 1.0000x reference)
//
#include <hip/hip_runtime.h>

#define NATOMS 128
#define BLOCK 256

#if defined(__has_builtin)
#if __has_builtin(__builtin_amdgcn_exp2f)
#define EXP2F(x) __builtin_amdgcn_exp2f(x)
#endif
#endif
#ifndef EXP2F
#define EXP2F(x) exp2f(x)
#endif

// Prep: build per-atom table of 8 floats:
//   A = (ax, ay, az, sb)  where a = c * log2e, sb = exp2(-0.5*|c|^2*log2e)
//   C = (cx*sb, cy*sb, cz*sb, 0)
// Then w_true(n,m) = sb_n * exp2(a_n . q_m + e_m), with e_m = -0.5|q_m|^2*log2e,
// and out_m = sum_n c_n w - q_m sum_n w = (sum C*w'') - q_m (sum sb*w''),
// where w'' = exp2(a.q + e_m).
__global__ void gnf_prep(const float* __restrict__ coords, float* __restrict__ tbl) {
    const float LOG2E = 1.44269504088896340736f;
    int n = threadIdx.x;
    if (n < NATOMS) {
        float cx = coords[n * 3 + 0];
        float cy = coords[n * 3 + 1];
        float cz = coords[n * 3 + 2];
        float b  = -0.5f * (cx * cx + cy * cy + cz * cz) * LOG2E;
        float sb = EXP2F(b);
        tbl[n * 8 + 0] = cx * LOG2E;
        tbl[n * 8 + 1] = cy * LOG2E;
        tbl[n * 8 + 2] = cz * LOG2E;
        tbl[n * 8 + 3] = sb;
        tbl[n * 8 + 4] = cx * sb;
        tbl[n * 8 + 5] = cy * sb;
        tbl[n * 8 + 6] = cz * sb;
        tbl[n * 8 + 7] = 0.0f;
    }
}

__global__ __launch_bounds__(BLOCK) void gnf_kernel(
    const float4* __restrict__ tbl,     // (128, 2) float4 — uniform -> s_load
    const float* __restrict__ query,    // (M,3)
    float* __restrict__ out,            // (M,3)
    int M)
{
    const float LOG2E = 1.44269504088896340736f;
    const int m = blockIdx.x * BLOCK + threadIdx.x;
    if (m >= M) return;

    const float qx = query[m * 3 + 0];
    const float qy = query[m * 3 + 1];
    const float qz = query[m * 3 + 2];
    const float eq = -0.5f * (qx * qx + qy * qy + qz * qz) * LOG2E;

    float sw = 0.0f, sx = 0.0f, sy = 0.0f, sz = 0.0f;

#pragma unroll 8
    for (int n = 0; n < NATOMS; ++n) {
        const float4 A = tbl[2 * n + 0];   // uniform: scalar loads, SGPR operands
        const float4 C = tbl[2 * n + 1];
        float t = fmaf(A.x, qx, fmaf(A.y, qy, fmaf(A.z, qz, eq)));
        float w = EXP2F(t);
        sw = fmaf(A.w, w, sw);
        sx = fmaf(C.x, w, sx);
        sy = fmaf(C.y, w, sy);
        sz = fmaf(C.z, w, sz);
    }

    out[m * 3 + 0] = fmaf(-qx, sw, sx);
    out[m * 3 + 1] = fmaf(-qy, sw, sy);
    out[m * 3 + 2] = fmaf(-qz, sw, sz);
}

extern "C" void kernel_launch(void* const* d_in, const int* in_sizes, int n_in,
                              void* d_out, int out_size, void* d_ws, size_t ws_size,
                              hipStream_t stream) {
    const float* coords = (const float*)d_in[0];
    const float* query  = (const float*)d_in[1];
    float* out = (float*)d_out;
    float* tbl = (float*)d_ws;          // 128 * 8 floats = 4 KB
    const int M = in_sizes[1] / 3;      // 262144

    gnf_prep<<<1, NATOMS, 0, stream>>>(coords, tbl);
    const int grid = (M + BLOCK - 1) / BLOCK;
    gnf_kernel<<<grid, BLOCK, 0, stream>>>((const float4*)tbl, query, out, M);
}

// Round 3
// 19.499 us; speedup vs baseline: 1.0487x; 1.0487x over previous
//
#include <hip/hip_runtime.h>

#define NATOMS 128
#define BLOCK 256
#define UN 4                    // atoms per batch
#define NB (NATOMS / UN)        // 32 batches

#if defined(__has_builtin)
#if __has_builtin(__builtin_amdgcn_exp2f)
#define EXP2F(x) __builtin_amdgcn_exp2f(x)
#endif
#endif
#ifndef EXP2F
#define EXP2F(x) exp2f(x)
#endif

struct Batch {
    float4 A[UN];   // a.x,a.y,a.z (log2e-folded), sb
    float4 C[UN];   // c*sb
};

__device__ __forceinline__ void loadBatch(const float4* __restrict__ sT, int b, Batch& B) {
#pragma unroll
    for (int i = 0; i < UN; ++i) {
        B.A[i] = sT[(b * UN + i) * 2 + 0];
        B.C[i] = sT[(b * UN + i) * 2 + 1];
    }
}

__device__ __forceinline__ void computeBatch(const Batch& B,
                                             float qx, float qy, float qz, float eq,
                                             float& sw, float& sx, float& sy, float& sz) {
#pragma unroll
    for (int i = 0; i < UN; ++i) {
        float t = fmaf(B.A[i].x, qx, fmaf(B.A[i].y, qy, fmaf(B.A[i].z, qz, eq)));
        float w = EXP2F(t);
        sw = fmaf(B.A[i].w, w, sw);
        sx = fmaf(B.C[i].x, w, sx);
        sy = fmaf(B.C[i].y, w, sy);
        sz = fmaf(B.C[i].z, w, sz);
    }
}

__global__ __launch_bounds__(BLOCK, 4) void gnf_kernel(
    const float* __restrict__ coords,   // (128,3)
    const float* __restrict__ query,    // (M,3)
    float* __restrict__ out,            // (M,3)
    int M)
{
    __shared__ float4 sT[NATOMS * 2];   // interleaved A,C per atom (4 KB)

    const float LOG2E = 1.44269504088896340736f;
    const int tid = threadIdx.x;
    const int m = blockIdx.x * BLOCK + tid;

    // Issue query loads before the barrier so they overlap table build.
    float qx = 0.f, qy = 0.f, qz = 0.f;
    if (m < M) {
        qx = query[m * 3 + 0];
        qy = query[m * 3 + 1];
        qz = query[m * 3 + 2];
    }

    if (tid < NATOMS) {
        float cx = coords[tid * 3 + 0];
        float cy = coords[tid * 3 + 1];
        float cz = coords[tid * 3 + 2];
        float b  = -0.5f * (cx * cx + cy * cy + cz * cz) * LOG2E;
        float sb = EXP2F(b);
        sT[tid * 2 + 0] = make_float4(cx * LOG2E, cy * LOG2E, cz * LOG2E, sb);
        sT[tid * 2 + 1] = make_float4(cx * sb, cy * sb, cz * sb, 0.0f);
    }
    __syncthreads();

    if (m >= M) return;

    const float eq = -0.5f * (qx * qx + qy * qy + qz * qz) * LOG2E;
    float sw = 0.0f, sx = 0.0f, sy = 0.0f, sz = 0.0f;

    Batch P, Q;
    loadBatch(sT, 0, P);
    for (int b = 0; b < NB; b += 2) {
        loadBatch(sT, b + 1, Q);                    // prefetch while computing P
        computeBatch(P, qx, qy, qz, eq, sw, sx, sy, sz);
        if (b + 2 < NB) loadBatch(sT, b + 2, P);    // prefetch while computing Q
        computeBatch(Q, qx, qy, qz, eq, sw, sx, sy, sz);
    }

    out[m * 3 + 0] = fmaf(-qx, sw, sx);
    out[m * 3 + 1] = fmaf(-qy, sw, sy);
    out[m * 3 + 2] = fmaf(-qz, sw, sz);
}

extern "C" void kernel_launch(void* const* d_in, const int* in_sizes, int n_in,
                              void* d_out, int out_size, void* d_ws, size_t ws_size,
                              hipStream_t stream) {
    const float* coords = (const float*)d_in[0];
    const float* query  = (const float*)d_in[1];
    float* out = (float*)d_out;
    const int M = in_sizes[1] / 3;      // 262144
    const int grid = (M + BLOCK - 1) / BLOCK;
    gnf_kernel<<<grid, BLOCK, 0, stream>>>(coords, query, out, M);
}

// Round 4
// 15.595 us; speedup vs baseline: 1.3112x; 1.2503x over previous
//
#include <hip/hip_runtime.h>

#define NATOMS 128
#define BLOCK 256
#define QPT 2
#define UN 4                    // atoms per batch
#define NB (NATOMS / UN)        // 32 batches

#if defined(__has_builtin)
#if __has_builtin(__builtin_amdgcn_exp2f)
#define EXP2F(x) __builtin_amdgcn_exp2f(x)
#endif
#endif
#ifndef EXP2F
#define EXP2F(x) exp2f(x)
#endif

// Per-atom table: A = (ax, ay, az, b) with a = c*log2e, b = -0.5*|c|^2*log2e.
// w = exp2(a.q + b + eq),  eq = -0.5*|q|^2*log2e
// out = sum_n (c_n - q) w_n = (sum a*w)*ln2 - q*(sum w)
// -> the SAME float4 feeds both exponent and accumulation: 1 ds_read_b128/atom.

struct Batch { float4 A[UN]; };

__device__ __forceinline__ void loadBatch(const float4* __restrict__ sT, int b, Batch& B) {
#pragma unroll
    for (int i = 0; i < UN; ++i) B.A[i] = sT[b * UN + i];
}

__device__ __forceinline__ void computeBatch(const Batch& B,
                                             const float* qx, const float* qy, const float* qz,
                                             const float* eq,
                                             float* sw, float* sx, float* sy, float* sz) {
#pragma unroll
    for (int i = 0; i < UN; ++i) {
        const float4 A = B.A[i];
#pragma unroll
        for (int k = 0; k < QPT; ++k) {
            float t = fmaf(A.x, qx[k], fmaf(A.y, qy[k], fmaf(A.z, qz[k], eq[k]))) + A.w;
            float w = EXP2F(t);
            sw[k] += w;
            sx[k] = fmaf(A.x, w, sx[k]);
            sy[k] = fmaf(A.y, w, sy[k]);
            sz[k] = fmaf(A.z, w, sz[k]);
        }
    }
}

__global__ __launch_bounds__(BLOCK) void gnf_kernel(
    const float* __restrict__ coords,   // (128,3)
    const float* __restrict__ query,    // (M,3)
    float* __restrict__ out,            // (M,3)
    int M)
{
    __shared__ float4 sT[NATOMS];       // 2 KB

    const float LOG2E = 1.44269504088896340736f;
    const float LN2   = 0.69314718055994530942f;
    const int tid = threadIdx.x;
    const int m0 = (blockIdx.x * BLOCK + tid) * QPT;

    // Query loads issued before the barrier (overlap table build).
    float qx[QPT], qy[QPT], qz[QPT], eq[QPT];
    float sw[QPT], sx[QPT], sy[QPT], sz[QPT];
    if (m0 + QPT <= M) {
        const float2* qp = (const float2*)(query + m0 * 3);   // 24B per thread, 8B aligned
        float2 v0 = qp[0], v1 = qp[1], v2 = qp[2];
        qx[0] = v0.x; qy[0] = v0.y; qz[0] = v1.x;
        qx[1] = v1.y; qy[1] = v2.x; qz[1] = v2.y;
    } else {
#pragma unroll
        for (int k = 0; k < QPT; ++k) {
            int m = m0 + k;
            qx[k] = (m < M) ? query[m * 3 + 0] : 0.f;
            qy[k] = (m < M) ? query[m * 3 + 1] : 0.f;
            qz[k] = (m < M) ? query[m * 3 + 2] : 0.f;
        }
    }
#pragma unroll
    for (int k = 0; k < QPT; ++k) {
        eq[k] = -0.5f * (qx[k] * qx[k] + qy[k] * qy[k] + qz[k] * qz[k]) * LOG2E;
        sw[k] = 0.f; sx[k] = 0.f; sy[k] = 0.f; sz[k] = 0.f;
    }

    if (tid < NATOMS) {
        float cx = coords[tid * 3 + 0];
        float cy = coords[tid * 3 + 1];
        float cz = coords[tid * 3 + 2];
        sT[tid] = make_float4(cx * LOG2E, cy * LOG2E, cz * LOG2E,
                              -0.5f * (cx * cx + cy * cy + cz * cz) * LOG2E);
    }
    __syncthreads();

    Batch P, Q;
    loadBatch(sT, 0, P);
    for (int b = 0; b < NB; b += 2) {
        loadBatch(sT, b + 1, Q);
        computeBatch(P, qx, qy, qz, eq, sw, sx, sy, sz);
        if (b + 2 < NB) loadBatch(sT, b + 2, P);
        computeBatch(Q, qx, qy, qz, eq, sw, sx, sy, sz);
    }

    if (m0 + QPT <= M) {
        float2* op = (float2*)(out + m0 * 3);
        float2 o0, o1, o2;
        o0.x = fmaf(sx[0], LN2, -(qx[0] * sw[0]));
        o0.y = fmaf(sy[0], LN2, -(qy[0] * sw[0]));
        o1.x = fmaf(sz[0], LN2, -(qz[0] * sw[0]));
        o1.y = fmaf(sx[1], LN2, -(qx[1] * sw[1]));
        o2.x = fmaf(sy[1], LN2, -(qy[1] * sw[1]));
        o2.y = fmaf(sz[1], LN2, -(qz[1] * sw[1]));
        op[0] = o0; op[1] = o1; op[2] = o2;
    } else {
#pragma unroll
        for (int k = 0; k < QPT; ++k) {
            int m = m0 + k;
            if (m < M) {
                out[m * 3 + 0] = fmaf(sx[k], LN2, -(qx[k] * sw[k]));
                out[m * 3 + 1] = fmaf(sy[k], LN2, -(qy[k] * sw[k]));
                out[m * 3 + 2] = fmaf(sz[k], LN2, -(qz[k] * sw[k]));
            }
        }
    }
}

extern "C" void kernel_launch(void* const* d_in, const int* in_sizes, int n_in,
                              void* d_out, int out_size, void* d_ws, size_t ws_size,
                              hipStream_t stream) {
    const float* coords = (const float*)d_in[0];
    const float* query  = (const float*)d_in[1];
    float* out = (float*)d_out;
    const int M = in_sizes[1] / 3;                     // 262144
    const int grid = (M + BLOCK * QPT - 1) / (BLOCK * QPT);  // 512
    gnf_kernel<<<grid, BLOCK, 0, stream>>>(coords, query, out, M);
}

// Round 5
// 15.561 us; speedup vs baseline: 1.3142x; 1.0022x over previous
//
#include <hip/hip_runtime.h>

#define NATOMS 128
#define BLOCK 256
#define UN 8                    // atoms per batch
#define NB (NATOMS / UN)        // 16 batches

#if defined(__has_builtin)
#if __has_builtin(__builtin_amdgcn_exp2f)
#define EXP2F(x) __builtin_amdgcn_exp2f(x)
#endif
#endif
#ifndef EXP2F
#define EXP2F(x) exp2f(x)
#endif

// Per-atom table: A = (ax, ay, az, b), a = c*log2e, b = -0.5*|c|^2*log2e.
// w = exp2(a.q + b + eq), eq = -0.5*|q|^2*log2e
// out = (sum a*w)*ln2 - q*(sum w)   -> one ds_read_b128 per atom.

struct Batch { float4 A[UN]; };

__device__ __forceinline__ void loadBatch(const float4* __restrict__ sT, int b, Batch& B) {
#pragma unroll
    for (int i = 0; i < UN; ++i) B.A[i] = sT[b * UN + i];
}

__device__ __forceinline__ void computeBatch(const Batch& B,
                                             float qx, float qy, float qz, float eq,
                                             float& sw, float& sx, float& sy, float& sz) {
#pragma unroll
    for (int i = 0; i < UN; ++i) {
        const float4 A = B.A[i];
        float t = fmaf(A.x, qx, fmaf(A.y, qy, fmaf(A.z, qz, eq))) + A.w;
        float w = EXP2F(t);
        sw += w;
        sx = fmaf(A.x, w, sx);
        sy = fmaf(A.y, w, sy);
        sz = fmaf(A.z, w, sz);
    }
}

__global__ __launch_bounds__(BLOCK, 4) void gnf_kernel(
    const float* __restrict__ coords,   // (128,3)
    const float* __restrict__ query,    // (M,3)
    float* __restrict__ out,            // (M,3)
    int M)
{
    __shared__ float4 sT[NATOMS];       // 2 KB

    const float LOG2E = 1.44269504088896340736f;
    const float LN2   = 0.69314718055994530942f;
    const int tid = threadIdx.x;
    const int m = blockIdx.x * BLOCK + tid;

    // Query load issued before the barrier (overlaps table build).
    float qx = 0.f, qy = 0.f, qz = 0.f;
    if (m < M) {
        qx = query[m * 3 + 0];
        qy = query[m * 3 + 1];
        qz = query[m * 3 + 2];
    }

    if (tid < NATOMS) {
        float cx = coords[tid * 3 + 0];
        float cy = coords[tid * 3 + 1];
        float cz = coords[tid * 3 + 2];
        sT[tid] = make_float4(cx * LOG2E, cy * LOG2E, cz * LOG2E,
                              -0.5f * (cx * cx + cy * cy + cz * cz) * LOG2E);
    }
    __syncthreads();

    if (m >= M) return;

    const float eq = -0.5f * (qx * qx + qy * qy + qz * qz) * LOG2E;
    float sw = 0.f, sx = 0.f, sy = 0.f, sz = 0.f;

    Batch P, Q;
    loadBatch(sT, 0, P);
    for (int b = 0; b < NB; b += 2) {
        loadBatch(sT, b + 1, Q);                    // prefetch while computing P
        computeBatch(P, qx, qy, qz, eq, sw, sx, sy, sz);
        if (b + 2 < NB) loadBatch(sT, b + 2, P);    // prefetch while computing Q
        computeBatch(Q, qx, qy, qz, eq, sw, sx, sy, sz);
    }

    out[m * 3 + 0] = fmaf(sx, LN2, -(qx * sw));
    out[m * 3 + 1] = fmaf(sy, LN2, -(qy * sw));
    out[m * 3 + 2] = fmaf(sz, LN2, -(qz * sw));
}

extern "C" void kernel_launch(void* const* d_in, const int* in_sizes, int n_in,
                              void* d_out, int out_size, void* d_ws, size_t ws_size,
                              hipStream_t stream) {
    const float* coords = (const float*)d_in[0];
    const float* query  = (const float*)d_in[1];
    float* out = (float*)d_out;
    const int M = in_sizes[1] / 3;              // 262144
    const int grid = (M + BLOCK - 1) / BLOCK;   // 1024
    gnf_kernel<<<grid, BLOCK, 0, stream>>>(coords, query, out, M);
}

// Round 6
// 15.272 us; speedup vs baseline: 1.3390x; 1.0189x over previous
//
#include <hip/hip_runtime.h>

#define NATOMS 128
#define BLOCK 256
#define QPT 2
#define UN 4                    // atoms per batch
#define NB (NATOMS / UN)        // 32 batches

#if defined(__has_builtin)
#if __has_builtin(__builtin_amdgcn_exp2f)
#define EXP2F(x) __builtin_amdgcn_exp2f(x)
#endif
#endif
#ifndef EXP2F
#define EXP2F(x) exp2f(x)
#endif

typedef float v2f __attribute__((ext_vector_type(2)));

static __device__ __forceinline__ v2f splat2(float s) { v2f r = {s, s}; return r; }
static __device__ __forceinline__ v2f fma2(v2f a, v2f b, v2f c) {
    return __builtin_elementwise_fma(a, b, c);
}

// Per-atom table: A = (ax, ay, az, b), a = c*log2e, b = -0.5*|c|^2*log2e.
// w = exp2(a.q + b + eq), eq = -0.5*|q|^2*log2e
// out = (sum a*w)*ln2 - q*(sum w)   -> one ds_read_b128 per atom.
// Two query points per thread, processed as <2 x float> so the backend
// emits v_pk_fma_f32 / v_pk_add_f32 (full-rate packed fp32 on CDNA).

struct Batch { float4 A[UN]; };

__device__ __forceinline__ void loadBatch(const float4* __restrict__ sT, int b, Batch& B) {
#pragma unroll
    for (int i = 0; i < UN; ++i) B.A[i] = sT[b * UN + i];
}

__device__ __forceinline__ void computeBatch(const Batch& B,
                                             v2f qx, v2f qy, v2f qz, v2f eq,
                                             v2f& sw, v2f& sx, v2f& sy, v2f& sz) {
#pragma unroll
    for (int i = 0; i < UN; ++i) {
        const float4 A = B.A[i];
        v2f t = fma2(splat2(A.x), qx, fma2(splat2(A.y), qy, fma2(splat2(A.z), qz, eq)));
        t += splat2(A.w);
        v2f w;
        w.x = EXP2F(t.x);
        w.y = EXP2F(t.y);
        sw += w;
        sx = fma2(splat2(A.x), w, sx);
        sy = fma2(splat2(A.y), w, sy);
        sz = fma2(splat2(A.z), w, sz);
    }
}

__global__ __launch_bounds__(BLOCK) void gnf_kernel(
    const float* __restrict__ coords,   // (128,3)
    const float* __restrict__ query,    // (M,3)
    float* __restrict__ out,            // (M,3)
    int M)
{
    __shared__ float4 sT[NATOMS];       // 2 KB

    const float LOG2E = 1.44269504088896340736f;
    const float LN2   = 0.69314718055994530942f;
    const int tid = threadIdx.x;
    const int m0 = (blockIdx.x * BLOCK + tid) * QPT;

    // Vectorized query load (24 B/thread), issued before the barrier.
    v2f qx, qy, qz;
    if (m0 + QPT <= M) {
        const float2* qp = (const float2*)(query + m0 * 3);
        float2 v0 = qp[0], v1 = qp[1], v2 = qp[2];
        qx.x = v0.x; qy.x = v0.y; qz.x = v1.x;
        qx.y = v1.y; qy.y = v2.x; qz.y = v2.y;
    } else {
        qx = splat2(0.f); qy = splat2(0.f); qz = splat2(0.f);
#pragma unroll
        for (int k = 0; k < QPT; ++k) {
            int m = m0 + k;
            if (m < M) {
                qx[k] = query[m * 3 + 0];
                qy[k] = query[m * 3 + 1];
                qz[k] = query[m * 3 + 2];
            }
        }
    }

    if (tid < NATOMS) {
        float cx = coords[tid * 3 + 0];
        float cy = coords[tid * 3 + 1];
        float cz = coords[tid * 3 + 2];
        sT[tid] = make_float4(cx * LOG2E, cy * LOG2E, cz * LOG2E,
                              -0.5f * (cx * cx + cy * cy + cz * cz) * LOG2E);
    }
    __syncthreads();

    v2f eq = (qx * qx + qy * qy + qz * qz) * splat2(-0.5f * LOG2E);
    v2f sw = splat2(0.f), sx = splat2(0.f), sy = splat2(0.f), sz = splat2(0.f);

    Batch P, Q;
    loadBatch(sT, 0, P);
    for (int b = 0; b < NB; b += 2) {
        loadBatch(sT, b + 1, Q);                    // prefetch while computing P
        computeBatch(P, qx, qy, qz, eq, sw, sx, sy, sz);
        if (b + 2 < NB) loadBatch(sT, b + 2, P);    // prefetch while computing Q
        computeBatch(Q, qx, qy, qz, eq, sw, sx, sy, sz);
    }

    if (m0 + QPT <= M) {
        float2* op = (float2*)(out + m0 * 3);
        float2 o0, o1, o2;
        o0.x = fmaf(sx.x, LN2, -(qx.x * sw.x));
        o0.y = fmaf(sy.x, LN2, -(qy.x * sw.x));
        o1.x = fmaf(sz.x, LN2, -(qz.x * sw.x));
        o1.y = fmaf(sx.y, LN2, -(qx.y * sw.y));
        o2.x = fmaf(sy.y, LN2, -(qy.y * sw.y));
        o2.y = fmaf(sz.y, LN2, -(qz.y * sw.y));
        op[0] = o0; op[1] = o1; op[2] = o2;
    } else {
#pragma unroll
        for (int k = 0; k < QPT; ++k) {
            int m = m0 + k;
            if (m < M) {
                out[m * 3 + 0] = fmaf(sx[k], LN2, -(qx[k] * sw[k]));
                out[m * 3 + 1] = fmaf(sy[k], LN2, -(qy[k] * sw[k]));
                out[m * 3 + 2] = fmaf(sz[k], LN2, -(qz[k] * sw[k]));
            }
        }
    }
}

extern "C" void kernel_launch(void* const* d_in, const int* in_sizes, int n_in,
                              void* d_out, int out_size, void* d_ws, size_t ws_size,
                              hipStream_t stream) {
    const float* coords = (const float*)d_in[0];
    const float* query  = (const float*)d_in[1];
    float* out = (float*)d_out;
    const int M = in_sizes[1] / 3;                           // 262144
    const int grid = (M + BLOCK * QPT - 1) / (BLOCK * QPT);  // 512
    gnf_kernel<<<grid, BLOCK, 0, stream>>>(coords, query, out, M);
}